// Round 1
// baseline (365.098 us; speedup 1.0000x reference)
//
#include <hip/hip_runtime.h>
#include <cstdint>
#include <cstddef>

// ---------------------------------------------------------------------------
// LSA transformer block: x += attn(LN1(x)); x += MLP(LN2(x))
// B=8, N=2048, C=256, H=8, D=32, HID=1024
// All matmuls in bf16 MFMA (16x16x32), accumulate fp32.
// ---------------------------------------------------------------------------

typedef __bf16 bf16x8 __attribute__((ext_vector_type(8)));
typedef __bf16 bf16x4 __attribute__((ext_vector_type(4)));
typedef float  f32x4  __attribute__((ext_vector_type(4)));

#define BN_TOK   2048
#define CC       256
#define HH       8
#define DD       32
#define HID_DIM  1024
#define MROWS    16384   // B*N

// ws layout (bytes)
#define OFF_W    0u          // 786432 bf16 weights   (1.5 MB)
#define OFF_A    1572864u    // 16384x256 bf16        (8 MB)   ln1 out / attn out / ln2 out
#define OFF_QKV  9961472u    // 16384x768 bf16        (24 MB)  qkv; later x1 fp32 (16 MB)
#define OFF_H    35127296u   // 16384x1024 bf16       (32 MB)
// weight element offsets inside OFF_W region
#define WOFF_QKV 0
#define WOFF_PRJ 196608
#define WOFF_FC1 262144
#define WOFF_FC2 524288

// -------------------------------- weight cvt -------------------------------
__global__ __launch_bounds__(256) void cvt_w_kernel(
    const float* __restrict__ q, const float* __restrict__ p,
    const float* __restrict__ f1, const float* __restrict__ f2,
    __bf16* __restrict__ dst)
{
    int i = (blockIdx.x * 256 + threadIdx.x) * 4;   // 786432 total elems
    const float* src; int off;
    if (i < 196608)      { src = q;  off = 0; }
    else if (i < 262144) { src = p;  off = 196608; }
    else if (i < 524288) { src = f1; off = 262144; }
    else                 { src = f2; off = 524288; }
    float4 v = *(const float4*)(src + (i - off));
    bf16x4 o;
    o[0] = (__bf16)v.x; o[1] = (__bf16)v.y; o[2] = (__bf16)v.z; o[3] = (__bf16)v.w;
    *(bf16x4*)(dst + i) = o;
}

// -------------------------------- layernorm --------------------------------
// one wave per row of 256 fp32; output bf16
__global__ __launch_bounds__(256) void ln_kernel(
    const float* __restrict__ x, const float* __restrict__ g,
    const float* __restrict__ b, __bf16* __restrict__ y)
{
    const int lane = threadIdx.x & 63;
    const int row  = blockIdx.x * 4 + (threadIdx.x >> 6);
    const float4 xv = *(const float4*)(x + (size_t)row * CC + lane * 4);
    float s  = xv.x + xv.y + xv.z + xv.w;
    float s2 = xv.x*xv.x + xv.y*xv.y + xv.z*xv.z + xv.w*xv.w;
#pragma unroll
    for (int m = 1; m < 64; m <<= 1) {
        s  += __shfl_xor(s,  m);
        s2 += __shfl_xor(s2, m);
    }
    const float mean = s * (1.0f / 256.0f);
    const float var  = fmaxf(s2 * (1.0f / 256.0f) - mean * mean, 0.0f);
    const float rstd = rsqrtf(var + 1e-5f);
    const float4 gv = *(const float4*)(g + lane * 4);
    const float4 bv = *(const float4*)(b + lane * 4);
    bf16x4 o;
    o[0] = (__bf16)((xv.x - mean) * rstd * gv.x + bv.x);
    o[1] = (__bf16)((xv.y - mean) * rstd * gv.y + bv.y);
    o[2] = (__bf16)((xv.z - mean) * rstd * gv.z + bv.z);
    o[3] = (__bf16)((xv.w - mean) * rstd * gv.w + bv.w);
    *(bf16x4*)(y + (size_t)row * CC + lane * 4) = o;
}

// -------------------------------- GEMM -------------------------------------
// out[m][n] = sum_k A[m][k] * W[n][k]  (+bias, +gelu, +res), A:MxK bf16, W:NxK bf16
// 64x64 tile, BK=32, 4 waves (2x2), each wave 32x32 via 2x2 mfma 16x16x32 frags.
template<int BIAS, int GELU, int RES, int OUTBF>
__global__ __launch_bounds__(256) void gemm_ep(
    const __bf16* __restrict__ A, const __bf16* __restrict__ W,
    const float* __restrict__ bias, const float* __restrict__ res,
    void* __restrict__ outp, int M, int N, int K)
{
    __shared__ __align__(16) __bf16 As[64][40];
    __shared__ __align__(16) __bf16 Bs[64][40];
    const int tid  = threadIdx.x;
    const int lane = tid & 63;
    const int wid  = tid >> 6;
    const int wr   = wid >> 1, wc = wid & 1;
    const int fr   = lane & 15, fg = lane >> 4;
    const int tm   = blockIdx.x * 64, tn = blockIdx.y * 64;
    const int srow = tid >> 2, sk = (tid & 3) * 8;

    f32x4 acc[2][2];
    const f32x4 vz = {0.f, 0.f, 0.f, 0.f};
#pragma unroll
    for (int mi = 0; mi < 2; ++mi)
#pragma unroll
        for (int nj = 0; nj < 2; ++nj) acc[mi][nj] = vz;

    for (int k0 = 0; k0 < K; k0 += 32) {
        *(bf16x8*)&As[srow][sk] = *(const bf16x8*)&A[(size_t)(tm + srow) * K + k0 + sk];
        *(bf16x8*)&Bs[srow][sk] = *(const bf16x8*)&W[(size_t)(tn + srow) * K + k0 + sk];
        __syncthreads();
        bf16x8 af[2], bf[2];
#pragma unroll
        for (int mi = 0; mi < 2; ++mi)
            af[mi] = *(const bf16x8*)&As[wr * 32 + mi * 16 + fr][fg * 8];
#pragma unroll
        for (int nj = 0; nj < 2; ++nj)
            bf[nj] = *(const bf16x8*)&Bs[wc * 32 + nj * 16 + fr][fg * 8];
#pragma unroll
        for (int mi = 0; mi < 2; ++mi)
#pragma unroll
            for (int nj = 0; nj < 2; ++nj)
                acc[mi][nj] = __builtin_amdgcn_mfma_f32_16x16x32_bf16(
                    af[mi], bf[nj], acc[mi][nj], 0, 0, 0);
        __syncthreads();
    }

    // epilogue: C/D layout col = fr, row = fg*4 + r
#pragma unroll
    for (int mi = 0; mi < 2; ++mi) {
#pragma unroll
        for (int nj = 0; nj < 2; ++nj) {
            const int col = tn + wc * 32 + nj * 16 + fr;
            float bv = 0.0f;
            if (BIAS) bv = bias[col];
#pragma unroll
            for (int r = 0; r < 4; ++r) {
                const int row = tm + wr * 32 + mi * 16 + fg * 4 + r;
                float v = acc[mi][nj][r];
                if (BIAS) v += bv;
                if (GELU) v = v * 0.5f * (1.0f + erff(v * 0.70710678118654752f));
                if (RES)  v += res[(size_t)row * N + col];
                if (OUTBF) ((__bf16*)outp)[(size_t)row * N + col] = (__bf16)v;
                else       ((float*)outp)[(size_t)row * N + col]  = v;
            }
        }
    }
}

// -------------------------------- attention --------------------------------
// qkv: (B*N) x 768 bf16, cols = s*256 + h*32 + d.  ao: (B*N) x 256 bf16.
// grid (32 qtiles, 64 bh). 4 waves/block, each wave owns 16 q rows.
// flash loop over 64-wide j tiles; diagonal masked.
__global__ __launch_bounds__(256) void attn_kernel(
    const __bf16* __restrict__ qkv, const float* __restrict__ scale_p,
    __bf16* __restrict__ ao)
{
    __shared__ __align__(16) __bf16 Ks[64][40];
    __shared__ __align__(16) __bf16 Vt[32][68];       // V transposed: [d][j]
    __shared__ __align__(16) __bf16 Ps[4][16][72];    // per-wave P tile

    const int tid  = threadIdx.x;
    const int lane = tid & 63;
    const int wid  = tid >> 6;
    const int fr   = lane & 15, fg = lane >> 4;
    const int qt   = blockIdx.x;           // 0..31
    const int bh   = blockIdx.y;           // 0..63
    const int b    = bh >> 3, h = bh & 7;
    const float sc = scale_p[0];
    const size_t base = (size_t)b * BN_TOK * 768;
    const int hq = h * 32, hk = 256 + h * 32, hv = 512 + h * 32;
    const int ib = qt * 64 + wid * 16;     // wave's q-row base

    // Q fragment (A-layout: row = fr, k = fg*8+e)
    const bf16x8 qf = *(const bf16x8*)&qkv[base + (size_t)(ib + fr) * 768 + hq + fg * 8];

    const f32x4 vz = {0.f, 0.f, 0.f, 0.f};
    f32x4 accd[2]; accd[0] = vz; accd[1] = vz;
    float mrun[4] = {-1e30f, -1e30f, -1e30f, -1e30f};
    float lrun[4] = {0.f, 0.f, 0.f, 0.f};

    const int sj = tid >> 2, sd = (tid & 3) * 8;   // staging: row sj, d-chunk sd

    for (int jt = 0; jt < 32; ++jt) {
        const int jb = jt * 64;
        __syncthreads();
        // stage K rows [jb, jb+64)
        *(bf16x8*)&Ks[sj][sd] = *(const bf16x8*)&qkv[base + (size_t)(jb + sj) * 768 + hk + sd];
        // stage V transposed
        bf16x8 vv = *(const bf16x8*)&qkv[base + (size_t)(jb + sj) * 768 + hv + sd];
#pragma unroll
        for (int e = 0; e < 8; ++e) Vt[sd + e][sj] = vv[e];
        __syncthreads();

        // S = Q K^T  (4 subtiles of 16 j)
        f32x4 s[4];
#pragma unroll
        for (int nj = 0; nj < 4; ++nj) {
            const bf16x8 kf = *(const bf16x8*)&Ks[nj * 16 + fr][fg * 8];
            s[nj] = __builtin_amdgcn_mfma_f32_16x16x32_bf16(qf, kf, vz, 0, 0, 0);
        }
        // scale + diagonal mask
#pragma unroll
        for (int nj = 0; nj < 4; ++nj) {
            const int gj = jb + nj * 16 + fr;
#pragma unroll
            for (int r = 0; r < 4; ++r) {
                const int gi = ib + fg * 4 + r;
                float v = s[nj][r] * sc;
                s[nj][r] = (gj == gi) ? -1e30f : v;
            }
        }
        // row max (reduce over 16 j-lanes)
        float mt[4];
#pragma unroll
        for (int r = 0; r < 4; ++r)
            mt[r] = fmaxf(fmaxf(s[0][r], s[1][r]), fmaxf(s[2][r], s[3][r]));
#pragma unroll
        for (int msk = 1; msk < 16; msk <<= 1)
#pragma unroll
            for (int r = 0; r < 4; ++r)
                mt[r] = fmaxf(mt[r], __shfl_xor(mt[r], msk));
        float al[4];
#pragma unroll
        for (int r = 0; r < 4; ++r) {
            const float mn = fmaxf(mrun[r], mt[r]);
            al[r]   = __expf(mrun[r] - mn);
            mrun[r] = mn;
        }
        // P = exp(S - m), row sum
        float st[4] = {0.f, 0.f, 0.f, 0.f};
#pragma unroll
        for (int nj = 0; nj < 4; ++nj)
#pragma unroll
            for (int r = 0; r < 4; ++r) {
                const float p = __expf(s[nj][r] - mrun[r]);
                s[nj][r] = p; st[r] += p;
            }
#pragma unroll
        for (int msk = 1; msk < 16; msk <<= 1)
#pragma unroll
            for (int r = 0; r < 4; ++r)
                st[r] += __shfl_xor(st[r], msk);
#pragma unroll
        for (int r = 0; r < 4; ++r) lrun[r] = lrun[r] * al[r] + st[r];
        // rescale accumulators
#pragma unroll
        for (int dh = 0; dh < 2; ++dh)
#pragma unroll
            for (int r = 0; r < 4; ++r) accd[dh][r] *= al[r];
        // P -> LDS (bf16) in A layout
#pragma unroll
        for (int nj = 0; nj < 4; ++nj)
#pragma unroll
            for (int r = 0; r < 4; ++r)
                Ps[wid][fg * 4 + r][nj * 16 + fr] = (__bf16)s[nj][r];
        // PV: accd[dh] += P(16x64) * V(64x16)
#pragma unroll
        for (int ka = 0; ka < 2; ++ka) {
            const bf16x8 pa = *(const bf16x8*)&Ps[wid][fr][ka * 32 + fg * 8];
#pragma unroll
            for (int dh = 0; dh < 2; ++dh) {
                const bf16x4 v0 = *(const bf16x4*)&Vt[dh * 16 + fr][ka * 32 + fg * 8];
                const bf16x4 v1 = *(const bf16x4*)&Vt[dh * 16 + fr][ka * 32 + fg * 8 + 4];
                bf16x8 vb;
                vb[0] = v0[0]; vb[1] = v0[1]; vb[2] = v0[2]; vb[3] = v0[3];
                vb[4] = v1[0]; vb[5] = v1[1]; vb[6] = v1[2]; vb[7] = v1[3];
                accd[dh] = __builtin_amdgcn_mfma_f32_16x16x32_bf16(pa, vb, accd[dh], 0, 0, 0);
            }
        }
    }
    // normalize + store: ao[b][i][h*32 + d]
#pragma unroll
    for (int dh = 0; dh < 2; ++dh)
#pragma unroll
        for (int r = 0; r < 4; ++r) {
            const int i = ib + fg * 4 + r;
            const float o = accd[dh][r] / lrun[r];
            ao[(size_t)(b * BN_TOK + i) * CC + h * 32 + dh * 16 + fr] = (__bf16)o;
        }
}

// -------------------------------- launch -----------------------------------
extern "C" void kernel_launch(void* const* d_in, const int* in_sizes, int n_in,
                              void* d_out, int out_size, void* d_ws, size_t ws_size,
                              hipStream_t stream)
{
    const float* x      = (const float*)d_in[0];
    const float* ln1_g  = (const float*)d_in[1];
    const float* ln1_b  = (const float*)d_in[2];
    const float* qkv_w  = (const float*)d_in[3];
    const float* scale  = (const float*)d_in[4];
    const float* proj_w = (const float*)d_in[5];
    const float* proj_b = (const float*)d_in[6];
    const float* ln2_g  = (const float*)d_in[7];
    const float* ln2_b  = (const float*)d_in[8];
    const float* fc1_w  = (const float*)d_in[9];
    const float* fc1_b  = (const float*)d_in[10];
    const float* fc2_w  = (const float*)d_in[11];
    const float* fc2_b  = (const float*)d_in[12];

    char* ws = (char*)d_ws;
    __bf16* wbf   = (__bf16*)(ws + OFF_W);
    __bf16* abf   = (__bf16*)(ws + OFF_A);
    __bf16* qkvbf = (__bf16*)(ws + OFF_QKV);
    float*  x1    = (float*) (ws + OFF_QKV);   // overlays qkv after attention
    __bf16* hbf   = (__bf16*)(ws + OFF_H);
    float*  out   = (float*)d_out;

    cvt_w_kernel<<<768, 256, 0, stream>>>(qkv_w, proj_w, fc1_w, fc2_w, wbf);
    ln_kernel<<<4096, 256, 0, stream>>>(x, ln1_g, ln1_b, abf);
    gemm_ep<0,0,0,1><<<dim3(256,12), 256, 0, stream>>>(
        abf, wbf + WOFF_QKV, nullptr, nullptr, qkvbf, MROWS, 768, 256);
    attn_kernel<<<dim3(32,64), 256, 0, stream>>>(qkvbf, scale, abf);
    gemm_ep<1,0,1,0><<<dim3(256,4), 256, 0, stream>>>(
        abf, wbf + WOFF_PRJ, proj_b, x, x1, MROWS, 256, 256);
    ln_kernel<<<4096, 256, 0, stream>>>(x1, ln2_g, ln2_b, abf);
    gemm_ep<1,1,0,1><<<dim3(256,16), 256, 0, stream>>>(
        abf, wbf + WOFF_FC1, fc1_b, nullptr, hbf, MROWS, HID_DIM, 256);
    gemm_ep<1,0,1,0><<<dim3(256,4), 256, 0, stream>>>(
        hbf, wbf + WOFF_FC2, fc2_b, x1, out, MROWS, 256, HID_DIM);
}

// Round 2
// 297.664 us; speedup vs baseline: 1.2265x; 1.2265x over previous
//
#include <hip/hip_runtime.h>
#include <cstdint>
#include <cstddef>

// ---------------------------------------------------------------------------
// LSA transformer block: x += attn(LN1(x)); x += MLP(LN2(x))
// B=8, N=2048, C=256, H=8, D=32, HID=1024
// ---------------------------------------------------------------------------

typedef __bf16 bf16x8 __attribute__((ext_vector_type(8)));
typedef __bf16 bf16x4 __attribute__((ext_vector_type(4)));
typedef float  f32x4  __attribute__((ext_vector_type(4)));

#define BN_TOK   2048
#define CC       256
#define HID_DIM  1024
#define MROWS    16384   // B*N

// ws layout (bytes)
#define OFF_W    0u          // 786432 bf16 weights   (1.5 MB)
#define OFF_A    1572864u    // 16384x256 bf16        (8 MB)
#define OFF_QKV  9961472u    // 16384x768 bf16 (24 MB); later x1 fp32 (16 MB)
#define OFF_H    35127296u   // 16384x1024 bf16       (32 MB)
#define WOFF_QKV 0
#define WOFF_PRJ 196608
#define WOFF_FC1 262144
#define WOFF_FC2 524288

__device__ __forceinline__ void gload_lds16(const __bf16* g, __bf16* l) {
    __builtin_amdgcn_global_load_lds(
        (const __attribute__((address_space(1))) void*)g,
        (__attribute__((address_space(3))) void*)l, 16, 0, 0);
}

// -------------------------------- weight cvt -------------------------------
__global__ __launch_bounds__(256) void cvt_w_kernel(
    const float* __restrict__ q, const float* __restrict__ p,
    const float* __restrict__ f1, const float* __restrict__ f2,
    __bf16* __restrict__ dst)
{
    int i = (blockIdx.x * 256 + threadIdx.x) * 4;
    const float* src; int off;
    if (i < 196608)      { src = q;  off = 0; }
    else if (i < 262144) { src = p;  off = 196608; }
    else if (i < 524288) { src = f1; off = 262144; }
    else                 { src = f2; off = 524288; }
    float4 v = *(const float4*)(src + (i - off));
    bf16x4 o;
    o[0] = (__bf16)v.x; o[1] = (__bf16)v.y; o[2] = (__bf16)v.z; o[3] = (__bf16)v.w;
    *(bf16x4*)(dst + i) = o;
}

// -------------------------------- layernorm --------------------------------
__global__ __launch_bounds__(256) void ln_kernel(
    const float* __restrict__ x, const float* __restrict__ g,
    const float* __restrict__ b, __bf16* __restrict__ y)
{
    const int lane = threadIdx.x & 63;
    const int row  = blockIdx.x * 4 + (threadIdx.x >> 6);
    const float4 xv = *(const float4*)(x + (size_t)row * CC + lane * 4);
    float s  = xv.x + xv.y + xv.z + xv.w;
    float s2 = xv.x*xv.x + xv.y*xv.y + xv.z*xv.z + xv.w*xv.w;
#pragma unroll
    for (int m = 1; m < 64; m <<= 1) {
        s  += __shfl_xor(s,  m);
        s2 += __shfl_xor(s2, m);
    }
    const float mean = s * (1.0f / 256.0f);
    const float var  = fmaxf(s2 * (1.0f / 256.0f) - mean * mean, 0.0f);
    const float rstd = rsqrtf(var + 1e-5f);
    const float4 gv = *(const float4*)(g + lane * 4);
    const float4 bv = *(const float4*)(b + lane * 4);
    bf16x4 o;
    o[0] = (__bf16)((xv.x - mean) * rstd * gv.x + bv.x);
    o[1] = (__bf16)((xv.y - mean) * rstd * gv.y + bv.y);
    o[2] = (__bf16)((xv.z - mean) * rstd * gv.z + bv.z);
    o[3] = (__bf16)((xv.w - mean) * rstd * gv.w + bv.w);
    *(bf16x4*)(y + (size_t)row * CC + lane * 4) = o;
}

// -------------------------------- GEMM (m97-style 128x128) -----------------
// out[m][n] = sum_k A[m][k]*W[n][k] (+bias,+gelu,+res). BK=32, 4 waves 2x2,
// each wave 64x64 (4x4 16x16x32 frags). global_load_lds w16, linear LDS.
template<int BIAS, int GELU, int RES, int OUTBF>
__global__ __launch_bounds__(256) void gemm128(
    const __bf16* __restrict__ A, const __bf16* __restrict__ W,
    const float* __restrict__ bias, const float* __restrict__ res,
    void* __restrict__ outp, int M, int N, int K)
{
    __shared__ __align__(16) __bf16 As[128 * 32];
    __shared__ __align__(16) __bf16 Bs[128 * 32];
    const int tid = threadIdx.x, lane = tid & 63, wid = tid >> 6;
    const int wr = wid >> 1, wc = wid & 1;
    const int fr = lane & 15, fg = lane >> 4;
    const int tm = blockIdx.x * 128, tn = blockIdx.y * 128;

    // staging: wave wid owns rows [wid*32, wid*32+32); LDS linear = lane*16B
    const int lrow = lane >> 2, lk = (lane & 3) * 8;
    const __bf16* gA = A + (size_t)(tm + wid * 32 + lrow) * K + lk;
    const __bf16* gB = W + (size_t)(tn + wid * 32 + lrow) * K + lk;
    __bf16* lA = As + wid * 1024;
    __bf16* lB = Bs + wid * 1024;
    const size_t rowK16 = (size_t)16 * K;

    f32x4 acc[4][4];
    const f32x4 vz = {0.f, 0.f, 0.f, 0.f};
#pragma unroll
    for (int mi = 0; mi < 4; ++mi)
#pragma unroll
        for (int nj = 0; nj < 4; ++nj) acc[mi][nj] = vz;

    for (int k0 = 0; k0 < K; k0 += 32) {
        gload_lds16(gA + k0,          lA);
        gload_lds16(gA + rowK16 + k0, lA + 512);
        gload_lds16(gB + k0,          lB);
        gload_lds16(gB + rowK16 + k0, lB + 512);
        __syncthreads();
        bf16x8 af[4], bfv[4];
#pragma unroll
        for (int mi = 0; mi < 4; ++mi)
            af[mi] = *(const bf16x8*)&As[(wr * 64 + mi * 16 + fr) * 32 + fg * 8];
#pragma unroll
        for (int nj = 0; nj < 4; ++nj)
            bfv[nj] = *(const bf16x8*)&Bs[(wc * 64 + nj * 16 + fr) * 32 + fg * 8];
#pragma unroll
        for (int mi = 0; mi < 4; ++mi)
#pragma unroll
            for (int nj = 0; nj < 4; ++nj)
                acc[mi][nj] = __builtin_amdgcn_mfma_f32_16x16x32_bf16(
                    af[mi], bfv[nj], acc[mi][nj], 0, 0, 0);
        __syncthreads();
    }

#pragma unroll
    for (int mi = 0; mi < 4; ++mi) {
#pragma unroll
        for (int nj = 0; nj < 4; ++nj) {
            const int col = tn + wc * 64 + nj * 16 + fr;
            float bv = 0.0f;
            if (BIAS) bv = bias[col];
#pragma unroll
            for (int r = 0; r < 4; ++r) {
                const int row = tm + wr * 64 + mi * 16 + fg * 4 + r;
                float v = acc[mi][nj][r];
                if (BIAS) v += bv;
                if (GELU) v = v * 0.5f * (1.0f + erff(v * 0.70710678118654752f));
                if (RES)  v += res[(size_t)row * N + col];
                if (OUTBF) ((__bf16*)outp)[(size_t)row * N + col] = (__bf16)v;
                else       ((float*)outp)[(size_t)row * N + col]  = v;
            }
        }
    }
}

// -------------------------------- attention --------------------------------
// No-max online softmax (|S| bounded ~1 by construction: exp can't overflow).
// 4 waves x 32 q-rows = 128 rows/block; 64-wide j tiles; diagonal masked only
// in the (rare) overlapping tile; row-sum reduced once at the end.
__global__ __launch_bounds__(256) void attn_kernel(
    const __bf16* __restrict__ qkv, const float* __restrict__ scale_p,
    __bf16* __restrict__ ao)
{
    __shared__ __align__(16) __bf16 Ks[64][40];
    __shared__ __align__(16) __bf16 Vt[32][72];       // V^T: [d][j], pad 72
    __shared__ __align__(16) __bf16 Ps[4][32][72];    // per-wave P tile

    const int tid = threadIdx.x, lane = tid & 63, wid = tid >> 6;
    const int fr = lane & 15, fg = lane >> 4;
    const int qt = blockIdx.x;             // 0..15
    const int bh = blockIdx.y;             // 0..63
    const int b = bh >> 3, h = bh & 7;
    const float c = scale_p[0] * 1.4426950408889634f;   // scale * log2(e)
    const size_t base = (size_t)b * BN_TOK * 768;
    const int hq = h * 32, hk = 256 + h * 32;
    const int ib = qt * 128 + wid * 32;    // wave's q-row base (32 rows)

    bf16x8 qf[2];
    qf[0] = *(const bf16x8*)&qkv[base + (size_t)(ib + fr) * 768 + hq + fg * 8];
    qf[1] = *(const bf16x8*)&qkv[base + (size_t)(ib + 16 + fr) * 768 + hq + fg * 8];

    const f32x4 vz = {0.f, 0.f, 0.f, 0.f};
    f32x4 accd[2][2];
    accd[0][0] = vz; accd[0][1] = vz; accd[1][0] = vz; accd[1][1] = vz;
    float psum[2][4] = {{0.f,0.f,0.f,0.f},{0.f,0.f,0.f,0.f}};

    const int sj = tid >> 2, sd = (tid & 3) * 8;
    const __bf16* kptr = qkv + base + (size_t)sj * 768 + hk + sd;
    const __bf16* vptr = kptr + 256;   // hv = hk + 256

    for (int jt = 0; jt < 32; ++jt) {
        const int jb = jt * 64;
        __syncthreads();
        *(bf16x8*)&Ks[sj][sd] = *(const bf16x8*)kptr;
        const bf16x8 vv = *(const bf16x8*)vptr;
#pragma unroll
        for (int e = 0; e < 8; ++e) Vt[sd + e][sj] = vv[e];
        kptr += (size_t)64 * 768; vptr += (size_t)64 * 768;
        __syncthreads();

        const bool dmask = (jb < ib + 32) && (ib < jb + 64);

#pragma unroll
        for (int mi = 0; mi < 2; ++mi) {
            f32x4 s[4];
#pragma unroll
            for (int nj = 0; nj < 4; ++nj) {
                const bf16x8 kf = *(const bf16x8*)&Ks[nj * 16 + fr][fg * 8];
                s[nj] = __builtin_amdgcn_mfma_f32_16x16x32_bf16(qf[mi], kf, vz, 0, 0, 0);
            }
#pragma unroll
            for (int nj = 0; nj < 4; ++nj)
#pragma unroll
                for (int r = 0; r < 4; ++r)
                    s[nj][r] = exp2f(s[nj][r] * c);
            if (dmask) {
                const int gi = ib + mi * 16 + fg * 4;
#pragma unroll
                for (int nj = 0; nj < 4; ++nj) {
                    const int gj = jb + nj * 16 + fr;
#pragma unroll
                    for (int r = 0; r < 4; ++r)
                        if (gj == gi + r) s[nj][r] = 0.f;
                }
            }
#pragma unroll
            for (int nj = 0; nj < 4; ++nj)
#pragma unroll
                for (int r = 0; r < 4; ++r) {
                    psum[mi][r] += s[nj][r];
                    Ps[wid][mi * 16 + fg * 4 + r][nj * 16 + fr] = (__bf16)s[nj][r];
                }
        }
        // PV: accd[mi][dh] += P(32x64) * V(64x32)
#pragma unroll
        for (int mi = 0; mi < 2; ++mi)
#pragma unroll
            for (int ka = 0; ka < 2; ++ka) {
                const bf16x8 pa = *(const bf16x8*)&Ps[wid][mi * 16 + fr][ka * 32 + fg * 8];
#pragma unroll
                for (int dh = 0; dh < 2; ++dh) {
                    const bf16x8 vb = *(const bf16x8*)&Vt[dh * 16 + fr][ka * 32 + fg * 8];
                    accd[mi][dh] = __builtin_amdgcn_mfma_f32_16x16x32_bf16(
                        pa, vb, accd[mi][dh], 0, 0, 0);
                }
            }
    }

    // one-time row-sum reduce across the 16 j-lanes
#pragma unroll
    for (int mi = 0; mi < 2; ++mi)
#pragma unroll
        for (int r = 0; r < 4; ++r) {
            float s = psum[mi][r];
            s += __shfl_xor(s, 1); s += __shfl_xor(s, 2);
            s += __shfl_xor(s, 4); s += __shfl_xor(s, 8);
            psum[mi][r] = s;
        }
#pragma unroll
    for (int mi = 0; mi < 2; ++mi)
#pragma unroll
        for (int dh = 0; dh < 2; ++dh)
#pragma unroll
            for (int r = 0; r < 4; ++r) {
                const int i = ib + mi * 16 + fg * 4 + r;
                const float o = accd[mi][dh][r] / psum[mi][r];
                ao[(size_t)(b * BN_TOK + i) * CC + h * 32 + dh * 16 + fr] = (__bf16)o;
            }
}

// -------------------------------- launch -----------------------------------
extern "C" void kernel_launch(void* const* d_in, const int* in_sizes, int n_in,
                              void* d_out, int out_size, void* d_ws, size_t ws_size,
                              hipStream_t stream)
{
    const float* x      = (const float*)d_in[0];
    const float* ln1_g  = (const float*)d_in[1];
    const float* ln1_b  = (const float*)d_in[2];
    const float* qkv_w  = (const float*)d_in[3];
    const float* scale  = (const float*)d_in[4];
    const float* proj_w = (const float*)d_in[5];
    const float* proj_b = (const float*)d_in[6];
    const float* ln2_g  = (const float*)d_in[7];
    const float* ln2_b  = (const float*)d_in[8];
    const float* fc1_w  = (const float*)d_in[9];
    const float* fc1_b  = (const float*)d_in[10];
    const float* fc2_w  = (const float*)d_in[11];
    const float* fc2_b  = (const float*)d_in[12];

    char* ws = (char*)d_ws;
    __bf16* wbf   = (__bf16*)(ws + OFF_W);
    __bf16* abf   = (__bf16*)(ws + OFF_A);
    __bf16* qkvbf = (__bf16*)(ws + OFF_QKV);
    float*  x1    = (float*) (ws + OFF_QKV);
    __bf16* hbf   = (__bf16*)(ws + OFF_H);
    float*  out   = (float*)d_out;

    cvt_w_kernel<<<768, 256, 0, stream>>>(qkv_w, proj_w, fc1_w, fc2_w, wbf);
    ln_kernel<<<4096, 256, 0, stream>>>(x, ln1_g, ln1_b, abf);
    gemm128<0,0,0,1><<<dim3(128,6), 256, 0, stream>>>(
        abf, wbf + WOFF_QKV, nullptr, nullptr, qkvbf, MROWS, 768, 256);
    attn_kernel<<<dim3(16,64), 256, 0, stream>>>(qkvbf, scale, abf);
    gemm128<1,0,1,0><<<dim3(128,2), 256, 0, stream>>>(
        abf, wbf + WOFF_PRJ, proj_b, x, x1, MROWS, 256, 256);
    ln_kernel<<<4096, 256, 0, stream>>>(x1, ln2_g, ln2_b, abf);
    gemm128<1,1,0,1><<<dim3(128,8), 256, 0, stream>>>(
        abf, wbf + WOFF_FC1, fc1_b, nullptr, hbf, MROWS, HID_DIM, 256);
    gemm128<1,0,1,0><<<dim3(128,2), 256, 0, stream>>>(
        hbf, wbf + WOFF_FC2, fc2_b, x1, out, MROWS, 256, HID_DIM);
}